// Round 3
// 38588.028 us; speedup vs baseline: 1.3564x; 1.3564x over previous
//
#include <hip/hip_runtime.h>

// ============================================================================
// Persistent pipelined LSTM-with-projection, MI355X (gfx950).
//
// R10 == R8/R9 + hang-proof watchdog. Rounds 1-2 died with "container
// failed twice" (no verdict). Audit found no deadlock/OOB vs R7 (which ran
// fine with the identical flag protocol), so either infra flaked twice or
// R8 hangs in a way inspection missed. Every flag-wait spin now has an
// iteration cap (~200k polls ~ 30ms, >>100x any legitimate wait); on expiry
// the WG sets an LDS abort word and returns uniformly. A real deadlock now
// ends in ~0.1s with passed:false + COUNTERS (diagnosis) instead of killing
// the container; if the protocol is sound the watchdog never fires.
//
// R8 vs R7 (52.3ms): gate GEMM moved to MFMA (bf16 3-split, fp32 accum).
//  (A) W and X staged as bf16 (hi,lo) pairs in FRAGMENT-LINEAR LDS layout:
//      each mfma_f32_16x16x32_bf16 operand is one ds_read_b128 at the LDS
//      BW floor -> the 2.16e9 GEMM bank-conflict cycles go away, and the
//      8192 v_fma_f32/thread/step (6.8us/SIMD issue) move to the matrix
//      pipe (~192 MFMA/wave/step ~ 1us). 3-split keeps fp32-class accuracy.
//  (B) h-ring global layout [b][p]: ring staging reads lane-contiguous in k.
//  (C) depth-2 named-register staging pipeline in both GEMM halves.
//  (D) activation remapped to the MFMA D-layout (col=lane&15, row=4*gq+reg).
// Flag protocol / broadcast / projection / WWIN back-pressure: unchanged.
// ============================================================================

#define B_    64
#define T_    1024
#define P_    256
#define H_    1024
#define L_    4
#define G4_   4096
#define NTHR  256
#define WWIN  8                     // h ring slots (power of two)
#define HSLOT (P_ * B_)             // 16384 floats per slot, layout [b][p]

// LDS (floats): WHI 16384 | WLO 16384 | XS 4096 | ACT 1024 | ABRT 4 = 37892
#define LDS_FLOATS 37892
#define LDS_BYTES  (LDS_FLOATS * 4)

// projection arena overlays XS+ACT (both dead during proj): 4896 <= 5120
#define PA_CH  36                   // padded row: 32 j + 4
#define PA_BUF (64 * PA_CH)         // 2304 floats per act chunk buffer
#define PW_OFF (2 * PA_BUF)         // 4608: two Whr chunk buffers of 144
#define PW_BUF (4 * PA_CH)          // 144

#define ACT_FLOATS ((size_t)L_ * H_ * B_)        // 1 MB act broadcast bufs
#define WDOG_CAP 200000             // ~30ms of polling before abort

struct alignas(16) F4 { float f[4]; };
typedef __attribute__((ext_vector_type(8))) short s8v;   // 8 bf16 (4 VGPRs)
typedef __attribute__((ext_vector_type(4))) float f4v;   // MFMA C/D

// ---- cross-WG data movement: compiler-tracked agent-scope accesses ---------
__device__ __forceinline__ void lda2(const float* p, float& a, float& b) {
  union { double d; float f[2]; } u;
  u.d = __hip_atomic_load((const double*)p, __ATOMIC_RELAXED,
                          __HIP_MEMORY_SCOPE_AGENT);
  a = u.f[0]; b = u.f[1];
}
__device__ __forceinline__ void sta2(float* p, float a, float b) {
  union { double d; float f[2]; } u;
  u.f[0] = a; u.f[1] = b;
  __hip_atomic_store((double*)p, u.d, __ATOMIC_RELAXED,
                     __HIP_MEMORY_SCOPE_AGENT);
}
__device__ __forceinline__ void sta(float* p, float v) {
  __hip_atomic_store(p, v, __ATOMIC_RELAXED, __HIP_MEMORY_SCOPE_AGENT);
}
__device__ __forceinline__ void drain_vm() {   // release: drain own stores
  asm volatile("s_waitcnt vmcnt(0)" ::: "memory");
}
// Hot-loop barrier: LDS visibility only -- does NOT drain vmcnt, so global
// prefetches survive. Compiler inserts vmcnt waits before each USE.
__device__ __forceinline__ void bar_lds() {
  asm volatile("s_waitcnt lgkmcnt(0)\n\ts_barrier" ::: "memory");
}

__device__ __forceinline__ float fsig(float x) {
  float e = __expf(-x);                        // saturation-safe
  return __builtin_amdgcn_rcpf(1.0f + e);
}
__device__ __forceinline__ float ftanh(float x) {
  float ax = fabsf(x);
  float e  = __expf(-2.0f * ax);               // in (0,1] -> no overflow/NaN
  float r  = (1.0f - e) * __builtin_amdgcn_rcpf(1.0f + e);
  return copysignf(r, x);
}
// ---- bf16 split helpers (round-to-nearest-even) ----------------------------
__device__ __forceinline__ ushort bf16_rne(float f) {
  uint u = __float_as_uint(f);
  uint r = u + 0x7FFFu + ((u >> 16) & 1u);
  return (ushort)(r >> 16);
}
__device__ __forceinline__ float bf16_to_f(ushort h) {
  return __uint_as_float(((uint)h) << 16);
}
// wave 0 polls 64 flags; others park at the barrier. Returns nonzero if the
// watchdog expired (WG-uniform) -- caller must return.
__device__ __forceinline__ int wait1(int* f, int tid, int target, int* abrt) {
  if (tid < 64) {
    int iters = 0;
    while (true) {
      int v = __hip_atomic_load(&f[tid], __ATOMIC_RELAXED, __HIP_MEMORY_SCOPE_AGENT);
      if (__ballot(v < target) == 0ull) break;
      if (++iters > WDOG_CAP) { if (tid == 0) *abrt = 1; break; }
      __builtin_amdgcn_s_sleep(2);
    }
  }
  __syncthreads();
  asm volatile("" ::: "memory");   // no hoisting data loads above the wait
  return *abrt;                    // LDS, uniform across WG
}

extern "C" __global__ void __launch_bounds__(NTHR, 1)
lstm_persistent(const float* __restrict__ y,
                const float* __restrict__ Wih,
                const float* __restrict__ Whh,
                const float* __restrict__ bih,
                const float* __restrict__ bhh,
                const float* __restrict__ Whr,
                const int*   __restrict__ mslp,
                float*       __restrict__ out,
                float*       __restrict__ hbuf,
                float*       __restrict__ actg,
                int*         __restrict__ hflag,
                int*         __restrict__ pflag)
{
  extern __shared__ float lds[];
  ushort* WHI  = (ushort*)lds;          // frag-linear: [(kt*4+g)*64+m] x 8 bf16
  ushort* WLO  = WHI + 32768;
  ushort* XS   = WLO + 32768;           // 2 bufs x (256 hi + 256 lo) frags
  float*  ACTf = lds + 36864;           // [16 cells][64 b]
  float*  PRJ  = lds + 32768;           // proj arena over XS+ACT (4896 floats)
  int*    ABRT = (int*)(lds + 37888);   // watchdog abort word

  const int bid = blockIdx.x;
  const int l   = (bid & 7) >> 1;       // layer on XCD pair {2l,2l+1}
  const int w   = ((bid & 1)) + 2 * (bid >> 3);   // 0..63, bijective
  const int J0  = w * 16;
  const int tid = threadIdx.x;
  const int msl = mslp[0];

  if (tid == 0) *ABRT = 0;

  // ---- one-time: gate weights -> bf16 (hi,lo) frag-linear LDS -------------
  // frag entry e = (kt*4+g)*64 + m : row m (= 4*cell+gate), k = kt*32+g*8..+7
  {
    const float* wih_l = Wih + (size_t)l * G4_ * P_;
    const float* whh_l = Whh + (size_t)l * G4_ * P_;
    for (int e = tid; e < 4096; e += NTHR) {
      int m  = e & 63;
      int g  = (e >> 6) & 3;
      int kt = e >> 8;
      int grow = (m & 3) * H_ + J0 + (m >> 2);    // torch gate order i,f,g,o
      int k = kt * 32 + g * 8;
      const float* src = (k < 256) ? (wih_l + (size_t)grow * P_ + k)
                                   : (whh_l + (size_t)grow * P_ + (k - 256));
      F4 aa = *(const F4*)src;
      F4 bb = *(const F4*)(src + 4);
      float xs8[8] = {aa.f[0], aa.f[1], aa.f[2], aa.f[3],
                      bb.f[0], bb.f[1], bb.f[2], bb.f[3]};
      s8v h8, l8;
#pragma unroll
      for (int i = 0; i < 8; ++i) {
        ushort hi = bf16_rne(xs8[i]);
        ushort lo = bf16_rne(xs8[i] - bf16_to_f(hi));
        h8[i] = (short)hi; l8[i] = (short)lo;
      }
      ((s8v*)WHI)[e] = h8;
      ((s8v*)WLO)[e] = l8;
    }
  }
  __syncthreads();

  // ---- thread mappings ----------------------------------------------------
  const int w4   = tid >> 6;            // wave 0..3 = M-stripe (16 gate rows)
  const int lane = tid & 63;
  const int gq   = lane >> 4;           // k-group of A/B fragment
  const int lm   = lane & 15;           // A row-in-stripe / D column (b)
  const int aix  = 16 * w4 + lm;        // A fragment row index 0..63
  const int cellj = 4 * w4 + gq;        // my cell 0..15 (from D layout)
  // staging: thread -> (b, k-octet)
  const int sb = tid >> 2;              // b 0..63
  const int sg = tid & 3;               // k-group 0..3 (k0 = 8*sg)
  // act repack / proj staging:
  const int jqr = tid >> 6, b_r = tid & 63;
  // proj compute:
  const int b_p = (w4 << 4) | (tid & 15);
  const int pw  = (tid >> 4) & 3;
  // proj Whr staging (threads 0..31 only):
  const int pws = tid >> 3, jqlw = tid & 7;   // valid when tid < 32

  float* hsrc = hbuf + (size_t)l * (WWIN * HSLOT);
  const float* hprv = (l > 0) ? (hbuf + (size_t)(l - 1) * (WWIN * HSLOT)) : hbuf;
  float* AGf = actg + (size_t)l * H_ * B_;   // [jq 0..255][b 0..63] of 4 floats

  float biasr[4];
#pragma unroll
  for (int gg = 0; gg < 4; ++gg) {
    int grow = gg * H_ + J0 + cellj;
    biasr[gg] = bih[l * G4_ + grow] + bhh[l * G4_ + grow];
  }

  float cst[4] = {0.f, 0.f, 0.f, 0.f};       // c-state: my cell at 4 b's

  for (int t = 0; t < T_; ++t) {
    f4v acc[4];
    {
      f4v z = {0.f, 0.f, 0.f, 0.f};
#pragma unroll
      for (int nt = 0; nt < 4; ++nt) acc[nt] = z;
    }

    // ---- MFMA chunk: kt = global k-tile 0..15, par = staging buffer ------
    auto gemm_chunk = [&](int kt, int par) {
      const s8v* WHIv = (const s8v*)WHI;
      const s8v* WLOv = (const s8v*)WLO;
      s8v ahi = WHIv[(kt * 4 + gq) * 64 + aix];
      s8v alo = WLOv[(kt * 4 + gq) * 64 + aix];
      const s8v* XB = (const s8v*)XS + par * 512;
      const int bbase = gq * 64 + lm;
#pragma unroll
      for (int nt = 0; nt < 4; ++nt) {
        s8v bhi = XB[bbase + nt * 16];
        s8v blo = XB[256 + bbase + nt * 16];
        acc[nt] = __builtin_amdgcn_mfma_f32_16x16x32_bf16(ahi, bhi, acc[nt], 0, 0, 0);
        acc[nt] = __builtin_amdgcn_mfma_f32_16x16x32_bf16(ahi, blo, acc[nt], 0, 0, 0);
        acc[nt] = __builtin_amdgcn_mfma_f32_16x16x32_bf16(alo, bhi, acc[nt], 0, 0, 0);
      }
    };

    // ---- staging: issue (global) / commit (cvt bf16 hi/lo -> frag LDS) ---
    auto ring_issue = [&](const float* src, int cc, F4& u, F4& v) {
      const float* p = src + (size_t)sb * P_ + ((cc & 7) << 5) + 8 * sg;
      lda2(p + 0, u.f[0], u.f[1]);
      lda2(p + 2, u.f[2], u.f[3]);
      lda2(p + 4, v.f[0], v.f[1]);
      lda2(p + 6, v.f[2], v.f[3]);
    };
    auto y_issue = [&](int cc, F4& u, F4& v) {
      const float* p = y + ((size_t)sb * T_ + t) * P_ + ((cc & 7) << 5) + 8 * sg;
      u = *(const F4*)p;
      v = *(const F4*)(p + 4);
    };
    auto commit_x = [&](int par, const F4& u, const F4& v) {
      s8v h8, l8;
#pragma unroll
      for (int i = 0; i < 4; ++i) {
        ushort hu = bf16_rne(u.f[i]);
        ushort lu = bf16_rne(u.f[i] - bf16_to_f(hu));
        ushort hv = bf16_rne(v.f[i]);
        ushort lv = bf16_rne(v.f[i] - bf16_to_f(hv));
        h8[i]     = (short)hu; l8[i]     = (short)lu;
        h8[i + 4] = (short)hv; l8[i + 4] = (short)lv;
      }
      s8v* XB = (s8v*)XS + par * 512;
      XB[sg * 64 + sb]       = h8;
      XB[256 + sg * 64 + sb] = l8;
    };

    // ---- depth-2 pipelined half (8 chunks), kt = c0..c0+7 ----------------
    auto run_half = [&](auto&& ISSUE, int c0) {
      F4 Au, Av, Bu, Bv;
      ISSUE(c0 + 0, Au, Av);
      ISSUE(c0 + 1, Bu, Bv);
      commit_x(0, Au, Av);
      bar_lds();
#pragma unroll
      for (int cc = 0; cc < 8; cc += 2) {
        if (cc + 2 < 8) ISSUE(c0 + cc + 2, Au, Av);
        gemm_chunk(c0 + cc, 0);
        commit_x(1, Bu, Bv);
        bar_lds();
        if (cc + 3 < 8) ISSUE(c0 + cc + 3, Bu, Bv);
        gemm_chunk(c0 + cc + 1, 1);
        if (cc + 2 < 8) commit_x(0, Au, Av);
        bar_lds();
      }
    };

    // ---- x-half of gate GEMM (k-tiles 0..7 = Wih) ------------------------
    if (l > 0) { if (wait1(hflag + (l - 1) * 64, tid, t, ABRT)) return; }
    if (l == 0) {
      run_half(y_issue, 0);
    } else {
      const float* xp = hprv + (size_t)(t & (WWIN - 1)) * HSLOT;
      auto xi = [&](int cc, F4& u, F4& v) { ring_issue(xp, cc, u, v); };
      run_half(xi, 0);
    }
    // ---- h-half (recurrent critical path; k-tiles 8..15 = Whh) -----------
    if (t > 0) {
      if (wait1(hflag + l * 64, tid, t - 1, ABRT)) return;
      const float* hp = hsrc + (size_t)((t - 1) & (WWIN - 1)) * HSLOT;
      auto hi_ = [&](int cc, F4& u, F4& v) { ring_issue(hp, cc, u, v); };
      run_half(hi_, 8);
    }

    // ---- activations + cell update (D: col=lane&15, row=4*gq+reg) --------
#pragma unroll
    for (int nt = 0; nt < 4; ++nt) {
      float vi = acc[nt][0] + biasr[0];
      float vf = acc[nt][1] + biasr[1];
      float vg = acc[nt][2] + biasr[2];
      float vo = acc[nt][3] + biasr[3];
      float ig = fsig(vi), fg = fsig(vf), g2 = ftanh(vg), og = fsig(vo);
      float cn = fmaf(fg, cst[nt], ig * g2);
      cst[nt] = cn;
      ACTf[cellj * 64 + nt * 16 + lm] = og * ftanh(cn);
    }
    bar_lds();

    // ---- broadcast acts: LDS -> global [jq][b][4], dwordx2 agent stores --
    {
      float a0 = ACTf[(4 * jqr + 0) * 64 + b_r];
      float a1 = ACTf[(4 * jqr + 1) * 64 + b_r];
      float a2 = ACTf[(4 * jqr + 2) * 64 + b_r];
      float a3 = ACTf[(4 * jqr + 3) * 64 + b_r];
      float* dst = AGf + ((size_t)(4 * w + jqr) * 64 + b_r) * 4;
      sta2(dst + 0, a0, a1);
      sta2(dst + 2, a2, a3);
    }
    drain_vm();          // release: own stores complete at coherence point
    __syncthreads();     // all waves drained
    if (tid == 0)
      __hip_atomic_store(&pflag[l * 64 + w], t, __ATOMIC_RELAXED, __HIP_MEMORY_SCOPE_AGENT);

    // ---- projection: h[b][4w+pw] = sum_j act[j][b]*Whr[4w+pw][j] ---------
    // Depth-2 register pipeline, NAMED F4 sets (no arrays -> no spills).
    if (wait1(pflag + l * 64, tid, t, ABRT)) return;

    F4 aAl, aAh, wA, aBl, aBh, wB;
    auto proj_issue = [&](int ch, F4& lo, F4& hi, F4& wv) {
      const float* a0 = AGf + ((size_t)(8 * ch + 2 * jqr) * 64 + b_r) * 4;
      lda2(a0 + 0,   lo.f[0], lo.f[1]);
      lda2(a0 + 2,   lo.f[2], lo.f[3]);
      lda2(a0 + 256, hi.f[0], hi.f[1]);
      lda2(a0 + 258, hi.f[2], hi.f[3]);
      if (tid < 32)      // Whr is read-only input: plain cached load
        wv = *(const F4*)(Whr + ((size_t)(l * P_ + 4 * w + pws)) * H_
                          + 32 * ch + 4 * jqlw);
    };
    auto proj_commit = [&](int bufi, F4& lo, F4& hi, F4& wv) {
      float* ab = PRJ + bufi * PA_BUF;
      *(F4*)&ab[b_r * PA_CH + 8 * jqr]     = lo;
      *(F4*)&ab[b_r * PA_CH + 8 * jqr + 4] = hi;
      if (tid < 32)
        *(F4*)&(PRJ + PW_OFF + bufi * PW_BUF)[pws * PA_CH + 4 * jqlw] = wv;
    };
    float s = 0.f;
    auto proj_comp = [&](int bufi) {
      const float* ab = PRJ + bufi * PA_BUF + b_p * PA_CH;
      const float* wb = PRJ + PW_OFF + bufi * PW_BUF + pw * PA_CH;
#pragma unroll
      for (int jj = 0; jj < 8; ++jj) {
        F4 a  = *(const F4*)&ab[4 * jj];
        F4 wv = *(const F4*)&wb[4 * jj];
        s = fmaf(a.f[0], wv.f[0], s);
        s = fmaf(a.f[1], wv.f[1], s);
        s = fmaf(a.f[2], wv.f[2], s);
        s = fmaf(a.f[3], wv.f[3], s);
      }
    };

    proj_issue(0, aAl, aAh, wA);
    proj_issue(1, aBl, aBh, wB);
    proj_commit(0, aAl, aAh, wA);
    bar_lds();
    for (int ch = 0; ch < 32; ch += 2) {
      // even: compute ch from buf0; commit ch+1 (B set -> buf1); refill A
      if (ch + 2 < 32) proj_issue(ch + 2, aAl, aAh, wA);
      proj_comp(0);
      if (ch + 1 < 32) proj_commit(1, aBl, aBh, wB);
      bar_lds();
      // odd: compute ch+1 from buf1; commit ch+2 (A set -> buf0); refill B
      if (ch + 3 < 32) proj_issue(ch + 3, aBl, aBh, wB);
      if (ch + 1 < 32) proj_comp(1);
      if (ch + 2 < 32) proj_commit(0, aAl, aAh, wA);
      bar_lds();
    }

    // ---- emit h (ring [b][p], agent store) + output ----------------------
    if (l < 3) {                         // ring back-pressure
      if (wait1(hflag + (l + 1) * 64, tid, t - WWIN, ABRT)) return;
    }
    sta(hsrc + (size_t)(t & (WWIN - 1)) * HSLOT + (size_t)b_p * P_ + (4 * w + pw), s);
    if (l == 3 && t >= msl)
      out[((size_t)b_p * (T_ - msl) + (t - msl)) * P_ + 4 * w + pw] = s;
    drain_vm();          // release h
    __syncthreads();
    if (tid == 0)
      __hip_atomic_store(&hflag[l * 64 + w], t, __ATOMIC_RELAXED, __HIP_MEMORY_SCOPE_AGENT);
  }
}

extern "C" void kernel_launch(void* const* d_in, const int* in_sizes, int n_in,
                              void* d_out, int out_size, void* d_ws, size_t ws_size,
                              hipStream_t stream) {
  const float* y   = (const float*)d_in[0];
  const float* Wih = (const float*)d_in[1];
  const float* Whh = (const float*)d_in[2];
  const float* bih = (const float*)d_in[3];
  const float* bhh = (const float*)d_in[4];
  const float* Whr = (const float*)d_in[5];
  const int*   msl = (const int*)d_in[6];
  float* out = (float*)d_out;

  // ws: [flags 4KB][act broadcast 1MB][h ring 2MB]  (~3 MB total)
  char*  ws    = (char*)d_ws;
  int*   flags = (int*)ws;
  float* actg  = (float*)(ws + 4096);
  float* hbuf  = (float*)(ws + 4096 + ACT_FLOATS * sizeof(float));

  hipMemsetAsync(flags, 0xFF, 4096, stream);   // epoch counters start at -1

  hipFuncSetAttribute(reinterpret_cast<const void*>(&lstm_persistent),
                      hipFuncAttributeMaxDynamicSharedMemorySize, LDS_BYTES);

  lstm_persistent<<<dim3(L_ * 64), dim3(NTHR), LDS_BYTES, stream>>>(
      y, Wih, Whh, bih, bhh, Whr, msl, out,
      hbuf, actg, flags /*hflag*/, flags + 256 /*pflag*/);
}

// Round 4
// 31004.013 us; speedup vs baseline: 1.6882x; 1.2446x over previous
//
#include <hip/hip_runtime.h>

// ============================================================================
// Persistent pipelined LSTM-with-projection, MI355X (gfx950).
//
// R11 vs R10 (38.6ms): latency surgery on the per-step critical cycle.
//  (A) x-half GEMM software-pipelined OUT of the recurrence cycle: x-half(t+1)
//      runs at the TAIL of iteration t (its input h(l-1,t+1)/y is ready ~WWIN
//      steps early). It now hides the own-layer sibling-hflag RT+skew instead
//      of adding ~2.5us to the cycle. Flag semantics identical; ring-safety
//      invariants re-audited (tail read precedes hflag=t+1 set).
//  (C) proj's wait-all-64-pflag replaced by PROGRESSIVE pipelined gating:
//      chunk order rotated to start at own pair (own flag trivially set,
//      partner ~simultaneous); each pair's 4 producer flags are loaded one
//      proj iteration (~600cy) ahead and verified per-wave (ballot) right
//      before the barrier that precedes that pair's issue -> flag RT hidden
//      under proj compute. Compiler fence after verify stops relaxed-atomic
//      hoisting of gated loads. All spins watchdog-capped + abort-aware:
//      a protocol bug terminates in ~100ms with passed:false + counters.
//
// R8 (vs R7 52.3ms): gate GEMM on MFMA (bf16 3-split hi/lo, fp32 accum),
// fragment-linear LDS for W and X, h-ring [b][p], depth-2 staging pipeline.
// ============================================================================

#define B_    64
#define T_    1024
#define P_    256
#define H_    1024
#define L_    4
#define G4_   4096
#define NTHR  256
#define WWIN  8                     // h ring slots (power of two)
#define HSLOT (P_ * B_)             // 16384 floats per slot, layout [b][p]

// LDS (floats): WHI 16384 | WLO 16384 | XS 4096 | ACT 1024 | ABRT 4 = 37892
#define LDS_FLOATS 37892
#define LDS_BYTES  (LDS_FLOATS * 4)

// projection arena overlays XS+ACT (both dead during proj): 4896 <= 5120
#define PA_CH  36                   // padded row: 32 j + 4
#define PA_BUF (64 * PA_CH)         // 2304 floats per act chunk buffer
#define PW_OFF (2 * PA_BUF)         // 4608: two Whr chunk buffers of 144
#define PW_BUF (4 * PA_CH)          // 144

#define ACT_FLOATS ((size_t)L_ * H_ * B_)        // 1 MB act broadcast bufs
#define WDOG_CAP 200000             // ~30ms of polling before abort

struct alignas(16) F4 { float f[4]; };
typedef __attribute__((ext_vector_type(8))) short s8v;   // 8 bf16 (4 VGPRs)
typedef __attribute__((ext_vector_type(4))) float f4v;   // MFMA C/D

// ---- cross-WG data movement: compiler-tracked agent-scope accesses ---------
__device__ __forceinline__ void lda2(const float* p, float& a, float& b) {
  union { double d; float f[2]; } u;
  u.d = __hip_atomic_load((const double*)p, __ATOMIC_RELAXED,
                          __HIP_MEMORY_SCOPE_AGENT);
  a = u.f[0]; b = u.f[1];
}
__device__ __forceinline__ void sta2(float* p, float a, float b) {
  union { double d; float f[2]; } u;
  u.f[0] = a; u.f[1] = b;
  __hip_atomic_store((double*)p, u.d, __ATOMIC_RELAXED,
                     __HIP_MEMORY_SCOPE_AGENT);
}
__device__ __forceinline__ void sta(float* p, float v) {
  __hip_atomic_store(p, v, __ATOMIC_RELAXED, __HIP_MEMORY_SCOPE_AGENT);
}
__device__ __forceinline__ void drain_vm() {   // release: drain own stores
  asm volatile("s_waitcnt vmcnt(0)" ::: "memory");
}
// Hot-loop barrier: LDS visibility only -- does NOT drain vmcnt, so global
// prefetches survive. Compiler inserts vmcnt waits before each USE.
__device__ __forceinline__ void bar_lds() {
  asm volatile("s_waitcnt lgkmcnt(0)\n\ts_barrier" ::: "memory");
}

__device__ __forceinline__ float fsig(float x) {
  float e = __expf(-x);                        // saturation-safe
  return __builtin_amdgcn_rcpf(1.0f + e);
}
__device__ __forceinline__ float ftanh(float x) {
  float ax = fabsf(x);
  float e  = __expf(-2.0f * ax);               // in (0,1] -> no overflow/NaN
  float r  = (1.0f - e) * __builtin_amdgcn_rcpf(1.0f + e);
  return copysignf(r, x);
}
// ---- bf16 split helpers (round-to-nearest-even) ----------------------------
__device__ __forceinline__ ushort bf16_rne(float f) {
  uint u = __float_as_uint(f);
  uint r = u + 0x7FFFu + ((u >> 16) & 1u);
  return (ushort)(r >> 16);
}
__device__ __forceinline__ float bf16_to_f(ushort h) {
  return __uint_as_float(((uint)h) << 16);
}
// wave 0 polls 64 flags; others park at the barrier. Returns nonzero if the
// watchdog expired (WG-uniform) -- caller must return.
__device__ __forceinline__ int wait1(int* f, int tid, int target, int* abrt) {
  if (tid < 64) {
    int it = 0;
    while (true) {
      int v = __hip_atomic_load(&f[tid], __ATOMIC_RELAXED, __HIP_MEMORY_SCOPE_AGENT);
      if (__ballot(v < target) == 0ull) break;
      if (++it > WDOG_CAP || *abrt) { if (tid == 0) *abrt = 1; break; }
      __builtin_amdgcn_s_sleep(2);
    }
  }
  __syncthreads();
  asm volatile("" ::: "memory");   // no hoisting data loads above the wait
  return *abrt;                    // LDS, uniform across WG
}

extern "C" __global__ void __launch_bounds__(NTHR, 1)
lstm_persistent(const float* __restrict__ y,
                const float* __restrict__ Wih,
                const float* __restrict__ Whh,
                const float* __restrict__ bih,
                const float* __restrict__ bhh,
                const float* __restrict__ Whr,
                const int*   __restrict__ mslp,
                float*       __restrict__ out,
                float*       __restrict__ hbuf,
                float*       __restrict__ actg,
                int*         __restrict__ hflag,
                int*         __restrict__ pflag)
{
  extern __shared__ float lds[];
  ushort* WHI  = (ushort*)lds;          // frag-linear: [(kt*4+g)*64+m] x 8 bf16
  ushort* WLO  = WHI + 32768;
  ushort* XS   = WLO + 32768;           // 2 bufs x (256 hi + 256 lo) frags
  float*  ACTf = lds + 36864;           // [16 cells][64 b]
  float*  PRJ  = lds + 32768;           // proj arena over XS+ACT (4896 floats)
  int*    ABRT = (int*)(lds + 37888);   // watchdog abort word

  const int bid = blockIdx.x;
  const int l   = (bid & 7) >> 1;       // layer on XCD pair {2l,2l+1}
  const int w   = ((bid & 1)) + 2 * (bid >> 3);   // 0..63, bijective
  const int J0  = w * 16;
  const int tid = threadIdx.x;
  const int msl = mslp[0];

  if (tid == 0) *ABRT = 0;

  // ---- one-time: gate weights -> bf16 (hi,lo) frag-linear LDS -------------
  // frag entry e = (kt*4+g)*64 + m : row m (= 4*cell+gate), k = kt*32+g*8..+7
  {
    const float* wih_l = Wih + (size_t)l * G4_ * P_;
    const float* whh_l = Whh + (size_t)l * G4_ * P_;
    for (int e = tid; e < 4096; e += NTHR) {
      int m  = e & 63;
      int g  = (e >> 6) & 3;
      int kt = e >> 8;
      int grow = (m & 3) * H_ + J0 + (m >> 2);    // torch gate order i,f,g,o
      int k = kt * 32 + g * 8;
      const float* src = (k < 256) ? (wih_l + (size_t)grow * P_ + k)
                                   : (whh_l + (size_t)grow * P_ + (k - 256));
      F4 aa = *(const F4*)src;
      F4 bb = *(const F4*)(src + 4);
      float xs8[8] = {aa.f[0], aa.f[1], aa.f[2], aa.f[3],
                      bb.f[0], bb.f[1], bb.f[2], bb.f[3]};
      s8v h8, l8;
#pragma unroll
      for (int i = 0; i < 8; ++i) {
        ushort hi = bf16_rne(xs8[i]);
        ushort lo = bf16_rne(xs8[i] - bf16_to_f(hi));
        h8[i] = (short)hi; l8[i] = (short)lo;
      }
      ((s8v*)WHI)[e] = h8;
      ((s8v*)WLO)[e] = l8;
    }
  }
  __syncthreads();

  // ---- thread mappings ----------------------------------------------------
  const int w4   = tid >> 6;            // wave 0..3 = M-stripe (16 gate rows)
  const int lane = tid & 63;
  const int gq   = lane >> 4;           // k-group of A/B fragment
  const int lm   = lane & 15;           // A row-in-stripe / D column (b)
  const int aix  = 16 * w4 + lm;        // A fragment row index 0..63
  const int cellj = 4 * w4 + gq;        // my cell 0..15 (from D layout)
  // staging: thread -> (b, k-octet)
  const int sb = tid >> 2;              // b 0..63
  const int sg = tid & 3;               // k-group 0..3 (k0 = 8*sg)
  // act repack / proj staging:
  const int jqr = tid >> 6, b_r = tid & 63;
  // proj compute:
  const int b_p = (w4 << 4) | (tid & 15);
  const int pw  = (tid >> 4) & 3;
  // proj Whr staging (threads 0..31 only):
  const int pws = tid >> 3, jqlw = tid & 7;   // valid when tid < 32

  float* hsrc = hbuf + (size_t)l * (WWIN * HSLOT);
  const float* hprv = (l > 0) ? (hbuf + (size_t)(l - 1) * (WWIN * HSLOT)) : hbuf;
  float* AGf = actg + (size_t)l * H_ * B_;   // [jq 0..255][b 0..63] of 4 floats

  float biasr[4];
#pragma unroll
  for (int gg = 0; gg < 4; ++gg) {
    int grow = gg * H_ + J0 + cellj;
    biasr[gg] = bih[l * G4_ + grow] + bhh[l * G4_ + grow];
  }

  float cst[4] = {0.f, 0.f, 0.f, 0.f};       // c-state: my cell at 4 b's
  f4v acc[4];                                // gate accum, lives across tail

  // ---- GEMM machinery (t-independent lambdas) -----------------------------
  auto gemm_chunk = [&](int kt, int par) {
    const s8v* WHIv = (const s8v*)WHI;
    const s8v* WLOv = (const s8v*)WLO;
    s8v ahi = WHIv[(kt * 4 + gq) * 64 + aix];
    s8v alo = WLOv[(kt * 4 + gq) * 64 + aix];
    const s8v* XB = (const s8v*)XS + par * 512;
    const int bbase = gq * 64 + lm;
#pragma unroll
    for (int nt = 0; nt < 4; ++nt) {
      s8v bhi = XB[bbase + nt * 16];
      s8v blo = XB[256 + bbase + nt * 16];
      acc[nt] = __builtin_amdgcn_mfma_f32_16x16x32_bf16(ahi, bhi, acc[nt], 0, 0, 0);
      acc[nt] = __builtin_amdgcn_mfma_f32_16x16x32_bf16(ahi, blo, acc[nt], 0, 0, 0);
      acc[nt] = __builtin_amdgcn_mfma_f32_16x16x32_bf16(alo, bhi, acc[nt], 0, 0, 0);
    }
  };
  auto ring_issue = [&](const float* src, int cc, F4& u, F4& v) {
    const float* p = src + (size_t)sb * P_ + ((cc & 7) << 5) + 8 * sg;
    lda2(p + 0, u.f[0], u.f[1]);
    lda2(p + 2, u.f[2], u.f[3]);
    lda2(p + 4, v.f[0], v.f[1]);
    lda2(p + 6, v.f[2], v.f[3]);
  };
  auto commit_x = [&](int par, const F4& u, const F4& v) {
    s8v h8, l8;
#pragma unroll
    for (int i = 0; i < 4; ++i) {
      ushort hu = bf16_rne(u.f[i]);
      ushort lu = bf16_rne(u.f[i] - bf16_to_f(hu));
      ushort hv = bf16_rne(v.f[i]);
      ushort lv = bf16_rne(v.f[i] - bf16_to_f(hv));
      h8[i]     = (short)hu; l8[i]     = (short)lu;
      h8[i + 4] = (short)hv; l8[i + 4] = (short)lv;
    }
    s8v* XB = (s8v*)XS + par * 512;
    XB[sg * 64 + sb]       = h8;
    XB[256 + sg * 64 + sb] = l8;
  };
  auto run_half = [&](auto&& ISSUE, int c0) {
    F4 Au, Av, Bu, Bv;
    ISSUE(c0 + 0, Au, Av);
    ISSUE(c0 + 1, Bu, Bv);
    commit_x(0, Au, Av);
    bar_lds();
#pragma unroll
    for (int cc = 0; cc < 8; cc += 2) {
      if (cc + 2 < 8) ISSUE(c0 + cc + 2, Au, Av);
      gemm_chunk(c0 + cc, 0);
      commit_x(1, Bu, Bv);
      bar_lds();
      if (cc + 3 < 8) ISSUE(c0 + cc + 3, Bu, Bv);
      gemm_chunk(c0 + cc + 1, 1);
      if (cc + 2 < 8) commit_x(0, Au, Av);
      bar_lds();
    }
  };
  // x-half of gate GEMM for step tt (zeroes acc; k-tiles 0..7 = Wih)
  auto do_xhalf = [&](int tt) {
    f4v z = {0.f, 0.f, 0.f, 0.f};
#pragma unroll
    for (int nt = 0; nt < 4; ++nt) acc[nt] = z;
    if (l == 0) {
      auto yi = [&](int cc, F4& u, F4& v) {
        const float* p = y + ((size_t)sb * T_ + tt) * P_ + ((cc & 7) << 5) + 8 * sg;
        u = *(const F4*)p;
        v = *(const F4*)(p + 4);
      };
      run_half(yi, 0);
    } else {
      const float* xp = hprv + (size_t)(tt & (WWIN - 1)) * HSLOT;
      auto xi = [&](int cc, F4& u, F4& v) { ring_issue(xp, cc, u, v); };
      run_half(xi, 0);
    }
  };

  // ---- prologue: x-half(0) ------------------------------------------------
  if (l > 0) { if (wait1(hflag + (l - 1) * 64, tid, 0, ABRT)) return; }
  do_xhalf(0);

  const int cbase = w >> 1;              // own proj chunk (rotation start)

  for (int t = 0; t < T_; ++t) {
    if (*ABRT) return;

    // ---- h-half (recurrent critical path; k-tiles 8..15 = Whh) -----------
    if (t > 0) {
      if (wait1(hflag + l * 64, tid, t - 1, ABRT)) return;
      const float* hp = hsrc + (size_t)((t - 1) & (WWIN - 1)) * HSLOT;
      auto hi_ = [&](int cc, F4& u, F4& v) { ring_issue(hp, cc, u, v); };
      run_half(hi_, 8);
    }

    // ---- activations + cell update (D: col=lane&15, row=4*gq+reg) --------
#pragma unroll
    for (int nt = 0; nt < 4; ++nt) {
      float vi = acc[nt][0] + biasr[0];
      float vf = acc[nt][1] + biasr[1];
      float vg = acc[nt][2] + biasr[2];
      float vo = acc[nt][3] + biasr[3];
      float ig = fsig(vi), fg = fsig(vf), g2 = ftanh(vg), og = fsig(vo);
      float cn = fmaf(fg, cst[nt], ig * g2);
      cst[nt] = cn;
      ACTf[cellj * 64 + nt * 16 + lm] = og * ftanh(cn);
    }
    bar_lds();

    // ---- broadcast acts: LDS -> global [jq][b][4], dwordx2 agent stores --
    {
      float a0 = ACTf[(4 * jqr + 0) * 64 + b_r];
      float a1 = ACTf[(4 * jqr + 1) * 64 + b_r];
      float a2 = ACTf[(4 * jqr + 2) * 64 + b_r];
      float a3 = ACTf[(4 * jqr + 3) * 64 + b_r];
      float* dst = AGf + ((size_t)(4 * w + jqr) * 64 + b_r) * 4;
      sta2(dst + 0, a0, a1);
      sta2(dst + 2, a2, a3);
    }
    drain_vm();          // release: own stores complete at coherence point
    __syncthreads();     // all waves drained
    if (tid == 0)
      __hip_atomic_store(&pflag[l * 64 + w], t, __ATOMIC_RELAXED, __HIP_MEMORY_SCOPE_AGENT);

    // ---- projection with progressive producer gating ---------------------
    // chunk order a(c) = (cbase+c)&31; pair {c,c+1} needs pflags
    // {2a(c)..2a(c)+3 mod 64}. Flags loaded ~1 proj iteration ahead; verified
    // per-wave (every wave gates its own issues -> no extra barrier needed).
    int* pfl = pflag + l * 64;
    auto achunk = [&](int c) { return (cbase + c) & 31; };
    auto fl_load = [&](int c) {
      int idx = (2 * achunk(c) + (lane & 3)) & 63;
      return __hip_atomic_load(&pfl[idx], __ATOMIC_RELAXED, __HIP_MEMORY_SCOPE_AGENT);
    };
    auto fl_verify = [&](int& have, int c) {
      int it = 0;
      while (__ballot(have < t) != 0ull) {
        if (++it > WDOG_CAP || *ABRT) { if (tid == 0) *ABRT = 1; break; }
        __builtin_amdgcn_s_sleep(2);
        have = fl_load(c);
      }
      asm volatile("" ::: "memory");   // gated loads must not hoist above
    };

    F4 aAl, aAh, wA, aBl, aBh, wB;
    auto proj_issue = [&](int ch, F4& lo, F4& hi, F4& wv) {
      const float* a0 = AGf + ((size_t)(8 * ch + 2 * jqr) * 64 + b_r) * 4;
      lda2(a0 + 0,   lo.f[0], lo.f[1]);
      lda2(a0 + 2,   lo.f[2], lo.f[3]);
      lda2(a0 + 256, hi.f[0], hi.f[1]);
      lda2(a0 + 258, hi.f[2], hi.f[3]);
      if (tid < 32)      // Whr is read-only input: plain cached load
        wv = *(const F4*)(Whr + ((size_t)(l * P_ + 4 * w + pws)) * H_
                          + 32 * ch + 4 * jqlw);
    };
    auto proj_commit = [&](int bufi, F4& lo, F4& hi, F4& wv) {
      float* ab = PRJ + bufi * PA_BUF;
      *(F4*)&ab[b_r * PA_CH + 8 * jqr]     = lo;
      *(F4*)&ab[b_r * PA_CH + 8 * jqr + 4] = hi;
      if (tid < 32)
        *(F4*)&(PRJ + PW_OFF + bufi * PW_BUF)[pws * PA_CH + 4 * jqlw] = wv;
    };
    float s = 0.f;
    auto proj_comp = [&](int bufi) {
      const float* ab = PRJ + bufi * PA_BUF + b_p * PA_CH;
      const float* wb = PRJ + PW_OFF + bufi * PW_BUF + pw * PA_CH;
#pragma unroll
      for (int jj = 0; jj < 8; ++jj) {
        F4 a  = *(const F4*)&ab[4 * jj];
        F4 wv = *(const F4*)&wb[4 * jj];
        s = fmaf(a.f[0], wv.f[0], s);
        s = fmaf(a.f[1], wv.f[1], s);
        s = fmaf(a.f[2], wv.f[2], s);
        s = fmaf(a.f[3], wv.f[3], s);
      }
    };

    {
      int fA = fl_load(0);
      fl_verify(fA, 0);                 // own pair: self set, partner ~now
      int fB = fl_load(2);
      proj_issue(achunk(0), aAl, aAh, wA);
      proj_issue(achunk(1), aBl, aBh, wB);
      fl_verify(fB, 2);                 // pair {2,3} before first bar
      proj_commit(0, aAl, aAh, wA);
      bar_lds();
      for (int c = 0; c < 32; c += 2) {
        int fN = 0;
        if (c + 4 < 32) fN = fl_load(c + 4);   // ~1 iter ahead of verify
        if (c + 2 < 32) proj_issue(achunk(c + 2), aAl, aAh, wA);
        proj_comp(0);
        if (c + 1 < 32) proj_commit(1, aBl, aBh, wB);
        bar_lds();
        if (c + 3 < 32) proj_issue(achunk(c + 3), aBl, aBh, wB);
        if (c + 1 < 32) proj_comp(1);
        if (c + 2 < 32) proj_commit(0, aAl, aAh, wA);
        if (c + 4 < 32) fl_verify(fN, c + 4);  // gate next iter's issues
        bar_lds();
      }
    }

    // ---- emit h (ring [b][p], agent store) + output ----------------------
    if (l < 3) {                         // ring back-pressure
      if (wait1(hflag + (l + 1) * 64, tid, t - WWIN, ABRT)) return;
    }
    sta(hsrc + (size_t)(t & (WWIN - 1)) * HSLOT + (size_t)b_p * P_ + (4 * w + pw), s);
    if (l == 3 && t >= msl)
      out[((size_t)b_p * (T_ - msl) + (t - msl)) * P_ + 4 * w + pw] = s;
    drain_vm();          // release h
    __syncthreads();
    if (tid == 0)
      __hip_atomic_store(&hflag[l * 64 + w], t, __ATOMIC_RELAXED, __HIP_MEMORY_SCOPE_AGENT);

    // ---- tail: x-half(t+1) off the critical cycle ------------------------
    if (t + 1 < T_) {
      if (l > 0) { if (wait1(hflag + (l - 1) * 64, tid, t + 1, ABRT)) return; }
      do_xhalf(t + 1);
    }
  }
}

extern "C" void kernel_launch(void* const* d_in, const int* in_sizes, int n_in,
                              void* d_out, int out_size, void* d_ws, size_t ws_size,
                              hipStream_t stream) {
  const float* y   = (const float*)d_in[0];
  const float* Wih = (const float*)d_in[1];
  const float* Whh = (const float*)d_in[2];
  const float* bih = (const float*)d_in[3];
  const float* bhh = (const float*)d_in[4];
  const float* Whr = (const float*)d_in[5];
  const int*   msl = (const int*)d_in[6];
  float* out = (float*)d_out;

  // ws: [flags 4KB][act broadcast 1MB][h ring 2MB]  (~3 MB total)
  char*  ws    = (char*)d_ws;
  int*   flags = (int*)ws;
  float* actg  = (float*)(ws + 4096);
  float* hbuf  = (float*)(ws + 4096 + ACT_FLOATS * sizeof(float));

  hipMemsetAsync(flags, 0xFF, 4096, stream);   // epoch counters start at -1

  hipFuncSetAttribute(reinterpret_cast<const void*>(&lstm_persistent),
                      hipFuncAttributeMaxDynamicSharedMemorySize, LDS_BYTES);

  lstm_persistent<<<dim3(L_ * 64), dim3(NTHR), LDS_BYTES, stream>>>(
      y, Wih, Whh, bih, bhh, Whr, msl, out,
      hbuf, actg, flags /*hflag*/, flags + 256 /*pflag*/);
}